// Round 1
// baseline (1563.481 us; speedup 1.0000x reference)
//
#include <hip/hip_runtime.h>
#include <math.h>

#define TB 16
#define TS 512
#define TD 768
#define TH 12
#define TDH 64
#define TNCH 3

// ---- GEMM tile config: 128x128 tile, BK=16, 256 threads, 8x8 micro ----
#define BM 128
#define BN 128
#define BK 16
#define TM 8
#define TN 8
#define LDT 132  // BM+4 pad: float4-aligned rows, breaks pow2 bank stride

#define SCALE 0.03608439182435161f  // 1/sqrt(768)

// ================= K1: qk = Ht @ W_qk + b_qk -> split Q,K =================
__global__ __launch_bounds__(256, 2)
void k1_qk(const float* __restrict__ A, const float* __restrict__ Bw,
           const float* __restrict__ bias, float* __restrict__ Q,
           float* __restrict__ Ko) {
  __shared__ float As[BK][LDT];
  __shared__ float Bs[BK][LDT];
  const int N = 2 * TD, Kd = TD;
  const int tid = threadIdx.x;
  const int tx = tid & 15, ty = tid >> 4;
  const int row0 = blockIdx.y * BM, col0 = blockIdx.x * BN;
  float acc[TM][TN];
#pragma unroll
  for (int i = 0; i < TM; i++)
#pragma unroll
    for (int j = 0; j < TN; j++) acc[i][j] = 0.f;

  for (int k0 = 0; k0 < Kd; k0 += BK) {
#pragma unroll
    for (int i = 0; i < 2; i++) {
      int idx = tid + i * 256;           // 0..511 (128 rows x 4 float4)
      int r = idx >> 2, c4 = idx & 3;
      float4 v = *(const float4*)&A[(size_t)(row0 + r) * Kd + k0 + c4 * 4];
      As[c4 * 4 + 0][r] = v.x; As[c4 * 4 + 1][r] = v.y;
      As[c4 * 4 + 2][r] = v.z; As[c4 * 4 + 3][r] = v.w;
    }
#pragma unroll
    for (int i = 0; i < 2; i++) {
      int idx = tid + i * 256;           // 0..511 (16 rows x 32 float4)
      int r = idx >> 5, c4 = idx & 31;
      float4 v = *(const float4*)&Bw[(size_t)(k0 + r) * N + col0 + c4 * 4];
      *(float4*)&Bs[r][c4 * 4] = v;
    }
    __syncthreads();
#pragma unroll
    for (int kk = 0; kk < BK; kk++) {
      float a[TM], b[TN];
      *(float4*)&a[0] = *(const float4*)&As[kk][ty * TM];
      *(float4*)&a[4] = *(const float4*)&As[kk][ty * TM + 4];
      *(float4*)&b[0] = *(const float4*)&Bs[kk][tx * TN];
      *(float4*)&b[4] = *(const float4*)&Bs[kk][tx * TN + 4];
#pragma unroll
      for (int i = 0; i < TM; i++)
#pragma unroll
        for (int j = 0; j < TN; j++) acc[i][j] += a[i] * b[j];
    }
    __syncthreads();
  }
#pragma unroll
  for (int i = 0; i < TM; i++) {
    int r = row0 + ty * TM + i;
#pragma unroll
    for (int j = 0; j < TN; j++) {
      int c = col0 + tx * TN + j;
      float v = acc[i][j] + bias[c];
      if (c < TD) Q[(size_t)r * TD + c] = v;
      else        Ko[(size_t)r * TD + (c - TD)] = v;
    }
  }
}

// ========== K2: fused scores -> softmax -> channel weights (Amean) ==========
// One block per (b, 8 q-rows). Wave w owns q-rows {w, w+4}; thread's k-slice
// is {lane + 64*j}. Scores land exactly on the softmax slice -> all in regs.
__global__ __launch_bounds__(256, 2)
void k2_attn(const float* __restrict__ Q, const float* __restrict__ Kg,
             const float* __restrict__ Ml, const float* __restrict__ am,
             float* __restrict__ Am) {
  __shared__ float Ks[64][68];   // +4 pad: float4-aligned, spreads banks
  __shared__ float Qs[8][64];
  __shared__ float ams[512];
  const int b = blockIdx.y;
  const int q0 = blockIdx.x * 8;
  const int tid = threadIdx.x;
  const int w = tid >> 6, lane = tid & 63;

  for (int i = tid; i < 512; i += 256) ams[i] = am[b * 512 + i];
  __syncthreads();

  float amqv[2];
  float Mv[TNCH][2][8];          // masked M tile, registers, reused all heads
#pragma unroll
  for (int rr = 0; rr < 2; rr++) {
    const int r = w + rr * 4;
    amqv[rr] = ams[q0 + r];
#pragma unroll
    for (int i = 0; i < TNCH; i++) {
      const float* Mrow = Ml + ((size_t)((b * TNCH + i) * TS + q0 + r)) * TS;
#pragma unroll
      for (int j = 0; j < 8; j++) {
        int k = lane + 64 * j;
        Mv[i][rr][j] = Mrow[k] * ams[k] * amqv[rr];
      }
    }
  }

  float acc[TNCH][2][8];
#pragma unroll
  for (int i = 0; i < TNCH; i++)
#pragma unroll
    for (int rr = 0; rr < 2; rr++)
#pragma unroll
      for (int j = 0; j < 8; j++) acc[i][rr][j] = 0.f;

  for (int h = 0; h < TH; h++) {
    __syncthreads();  // prev head done reading Qs
    for (int i = tid; i < 512; i += 256) {
      int r = i >> 6, d = i & 63;
      Qs[r][d] = Q[((size_t)(b * TS + q0 + r)) * TD + h * TDH + d];
    }
    float sreg[2][8];
    for (int t = 0; t < 8; t++) {
      __syncthreads();  // prev tile done reading Ks (t=0: Qs written)
#pragma unroll
      for (int i = 0; i < 4; i++) {
        int f4 = tid + i * 256;            // 0..1023
        int kk = f4 >> 4, d4 = f4 & 15;
        float4 v = *(const float4*)&Kg[((size_t)(b * TS + t * TDH + kk)) * TD + h * TDH + d4 * 4];
        *(float4*)&Ks[kk][d4 * 4] = v;
      }
      __syncthreads();
      float s0 = 0.f, s1 = 0.f;
#pragma unroll
      for (int d4 = 0; d4 < 16; d4++) {
        float4 kv = *(const float4*)&Ks[lane][d4 * 4];
        float4 qa = *(const float4*)&Qs[w][d4 * 4];
        float4 qb = *(const float4*)&Qs[w + 4][d4 * 4];
        s0 += kv.x * qa.x + kv.y * qa.y + kv.z * qa.z + kv.w * qa.w;
        s1 += kv.x * qb.x + kv.y * qb.y + kv.z * qb.z + kv.w * qb.w;
      }
      int kc = t * TDH + lane;
      float mterm = (1.f - ams[kc]) * (-1e9f);
      sreg[0][t] = s0 * SCALE + mterm;
      sreg[1][t] = s1 * SCALE + mterm;
    }
    // softmax (unnormalized) + per-channel renorm accumulate, all regs/shfl
#pragma unroll
    for (int rr = 0; rr < 2; rr++) {
      float mx = -3.0e38f;
#pragma unroll
      for (int j = 0; j < 8; j++) mx = fmaxf(mx, sreg[rr][j]);
#pragma unroll
      for (int off = 32; off > 0; off >>= 1) mx = fmaxf(mx, __shfl_xor(mx, off));
      float ex[8], Z = 0.f;
#pragma unroll
      for (int j = 0; j < 8; j++) { ex[j] = __expf(sreg[rr][j] - mx); Z += ex[j]; }
#pragma unroll
      for (int off = 32; off > 0; off >>= 1) Z += __shfl_xor(Z, off);
#pragma unroll
      for (int i = 0; i < TNCH; i++) {
        float dm = 0.f;
#pragma unroll
        for (int j = 0; j < 8; j++) dm += Mv[i][rr][j] * ex[j];
#pragma unroll
        for (int off = 32; off > 0; off >>= 1) dm += __shfl_xor(dm, off);
        const float winv = 1.f / (dm + 1e-10f * Z);
#pragma unroll
        for (int j = 0; j < 8; j++) acc[i][rr][j] += ex[j] * winv;
      }
    }
  }
  const float inv_h = 1.f / (float)TH;
#pragma unroll
  for (int rr = 0; rr < 2; rr++) {
    const int r = w + rr * 4;
#pragma unroll
    for (int i = 0; i < TNCH; i++) {
      float* Arow = Am + ((size_t)((i * TB + b) * TS + q0 + r)) * TS;
#pragma unroll
      for (int j = 0; j < 8; j++) {
        int k = lane + 64 * j;
        Arow[k] = Mv[i][rr][j] * acc[i][rr][j] * inv_h;
      }
    }
  }
}

// ============ K3: G[ch,b] = Amean[ch,b] (512x512) @ Ht[b] (512x768) ============
__global__ __launch_bounds__(256, 2)
void k3_feat(const float* __restrict__ Am, const float* __restrict__ Ht,
             float* __restrict__ G) {
  __shared__ float As[BK][LDT];
  __shared__ float Bs[BK][LDT];
  const int batch = blockIdx.z;            // ch*16 + b
  const int bidx = batch & 15;
  const float* A = Am + (size_t)batch * TS * TS;
  const float* Bw = Ht + (size_t)bidx * TS * TD;
  float* C = G + (size_t)batch * TS * TD;
  const int N = TD, Kd = TS;
  const int tid = threadIdx.x;
  const int tx = tid & 15, ty = tid >> 4;
  const int row0 = blockIdx.y * BM, col0 = blockIdx.x * BN;
  float acc[TM][TN];
#pragma unroll
  for (int i = 0; i < TM; i++)
#pragma unroll
    for (int j = 0; j < TN; j++) acc[i][j] = 0.f;

  for (int k0 = 0; k0 < Kd; k0 += BK) {
#pragma unroll
    for (int i = 0; i < 2; i++) {
      int idx = tid + i * 256;
      int r = idx >> 2, c4 = idx & 3;
      float4 v = *(const float4*)&A[(size_t)(row0 + r) * Kd + k0 + c4 * 4];
      As[c4 * 4 + 0][r] = v.x; As[c4 * 4 + 1][r] = v.y;
      As[c4 * 4 + 2][r] = v.z; As[c4 * 4 + 3][r] = v.w;
    }
#pragma unroll
    for (int i = 0; i < 2; i++) {
      int idx = tid + i * 256;
      int r = idx >> 5, c4 = idx & 31;
      float4 v = *(const float4*)&Bw[(size_t)(k0 + r) * N + col0 + c4 * 4];
      *(float4*)&Bs[r][c4 * 4] = v;
    }
    __syncthreads();
#pragma unroll
    for (int kk = 0; kk < BK; kk++) {
      float a[TM], b[TN];
      *(float4*)&a[0] = *(const float4*)&As[kk][ty * TM];
      *(float4*)&a[4] = *(const float4*)&As[kk][ty * TM + 4];
      *(float4*)&b[0] = *(const float4*)&Bs[kk][tx * TN];
      *(float4*)&b[4] = *(const float4*)&Bs[kk][tx * TN + 4];
#pragma unroll
      for (int i = 0; i < TM; i++)
#pragma unroll
        for (int j = 0; j < TN; j++) acc[i][j] += a[i] * b[j];
    }
    __syncthreads();
  }
#pragma unroll
  for (int i = 0; i < TM; i++) {
    int r = row0 + ty * TM + i;
#pragma unroll
    for (int j = 0; j < TN; j++) {
      int c = col0 + tx * TN + j;
      C[(size_t)r * TD + c] = acc[i][j];
    }
  }
}

// ==== K4: out = mean_ch relu(G_ch @ W_gat_ch + b_gat_ch) * am, 3 K-loops ====
__global__ __launch_bounds__(256, 2)
void k4_out(const float* __restrict__ G, const float* __restrict__ Wg,
            const float* __restrict__ bg, const float* __restrict__ am,
            float* __restrict__ out) {
  __shared__ float As[BK][LDT];
  __shared__ float Bs[BK][LDT];
  const int N = TD, Kd = TD;
  const int tid = threadIdx.x;
  const int tx = tid & 15, ty = tid >> 4;
  const int row0 = blockIdx.y * BM, col0 = blockIdx.x * BN;
  float osum[TM][TN];
#pragma unroll
  for (int i = 0; i < TM; i++)
#pragma unroll
    for (int j = 0; j < TN; j++) osum[i][j] = 0.f;

  for (int ch = 0; ch < TNCH; ch++) {
    const float* A = G + (size_t)ch * (TB * TS) * TD;
    const float* Bw = Wg + (size_t)ch * TD * TD;
    float acc[TM][TN];
#pragma unroll
    for (int i = 0; i < TM; i++)
#pragma unroll
      for (int j = 0; j < TN; j++) acc[i][j] = 0.f;

    for (int k0 = 0; k0 < Kd; k0 += BK) {
#pragma unroll
      for (int i = 0; i < 2; i++) {
        int idx = tid + i * 256;
        int r = idx >> 2, c4 = idx & 3;
        float4 v = *(const float4*)&A[(size_t)(row0 + r) * Kd + k0 + c4 * 4];
        As[c4 * 4 + 0][r] = v.x; As[c4 * 4 + 1][r] = v.y;
        As[c4 * 4 + 2][r] = v.z; As[c4 * 4 + 3][r] = v.w;
      }
#pragma unroll
      for (int i = 0; i < 2; i++) {
        int idx = tid + i * 256;
        int r = idx >> 5, c4 = idx & 31;
        float4 v = *(const float4*)&Bw[(size_t)(k0 + r) * N + col0 + c4 * 4];
        *(float4*)&Bs[r][c4 * 4] = v;
      }
      __syncthreads();
#pragma unroll
      for (int kk = 0; kk < BK; kk++) {
        float a[TM], b[TN];
        *(float4*)&a[0] = *(const float4*)&As[kk][ty * TM];
        *(float4*)&a[4] = *(const float4*)&As[kk][ty * TM + 4];
        *(float4*)&b[0] = *(const float4*)&Bs[kk][tx * TN];
        *(float4*)&b[4] = *(const float4*)&Bs[kk][tx * TN + 4];
#pragma unroll
        for (int i = 0; i < TM; i++)
#pragma unroll
          for (int j = 0; j < TN; j++) acc[i][j] += a[i] * b[j];
      }
      __syncthreads();
    }
#pragma unroll
    for (int i = 0; i < TM; i++)
#pragma unroll
      for (int j = 0; j < TN; j++) {
        int c = col0 + tx * TN + j;
        osum[i][j] += fmaxf(acc[i][j] + bg[ch * TD + c], 0.f);
      }
  }
#pragma unroll
  for (int i = 0; i < TM; i++) {
    int r = row0 + ty * TM + i;
    float amr = am[r] * (1.f / 3.f);
#pragma unroll
    for (int j = 0; j < TN; j++) {
      int c = col0 + tx * TN + j;
      out[(size_t)r * TD + c] = osum[i][j] * amr;
    }
  }
}

extern "C" void kernel_launch(void* const* d_in, const int* in_sizes, int n_in,
                              void* d_out, int out_size, void* d_ws, size_t ws_size,
                              hipStream_t stream) {
  const float* Ht    = (const float*)d_in[0];
  const float* Ml    = (const float*)d_in[1];
  const float* am    = (const float*)d_in[2];
  const float* W_qk  = (const float*)d_in[3];
  const float* b_qk  = (const float*)d_in[4];
  const float* W_gat = (const float*)d_in[5];
  const float* b_gat = (const float*)d_in[6];
  float* out = (float*)d_out;
  float* ws = (float*)d_ws;

  // ws layout (floats): Q[0, 6291456) K[6291456, 12582912)
  //                     Am[18874368, 31457280)
  //                     G [0, 18874368)  -- overlays dead Q/K after K2
  float* Q  = ws;
  float* Kb = ws + (size_t)TB * TS * TD;
  float* Am = ws + (size_t)3 * TB * TS * TD;
  float* G  = ws;

  k1_qk  <<<dim3(12, 64), 256, 0, stream>>>(Ht, W_qk, b_qk, Q, Kb);
  k2_attn<<<dim3(64, 16), 256, 0, stream>>>(Q, Kb, Ml, am, Am);
  k3_feat<<<dim3(6, 4, 48), 256, 0, stream>>>(Am, Ht, G);
  k4_out <<<dim3(6, 64), 256, 0, stream>>>(G, W_gat, b_gat, am, out);
}

// Round 2
// 834.592 us; speedup vs baseline: 1.8733x; 1.8733x over previous
//
#include <hip/hip_runtime.h>
#include <math.h>

typedef __attribute__((ext_vector_type(8))) short short8;
typedef __attribute__((ext_vector_type(4))) float floatx4;

#define TB 16
#define TS 512
#define TD 768
#define TH 12
#define TDH 64
#define TNCH 3

#define SCALE 0.03608439182435161f  // 1/sqrt(768)

#define LDA_S 40   // ushort stride: 32 k + 8 pad (16B-aligned rows, 2-way banks = free)
#define LDB_S 36   // ushort stride: 32 k + 4 pad (8B-aligned, conflict-free b64 reads)

__device__ __forceinline__ unsigned short f2bf(float f) {
  unsigned u = __float_as_uint(f);
  u += 0x7fffu + ((u >> 16) & 1u);   // round-to-nearest-even
  return (unsigned short)(u >> 16);
}
__device__ __forceinline__ unsigned f2bf2(float lo, float hi) {
  return (unsigned)f2bf(lo) | ((unsigned)f2bf(hi) << 16);
}

union U4 { uint4 u; short8 s; };

// ---- stage A tile (fp32 source, row-major, lda) -> As[r*LDA_S + k] (bf16) ----
__device__ __forceinline__ void stageA_f32(const float* __restrict__ A, int lda,
                                           int row0, int k0, int tid,
                                           unsigned short* As) {
#pragma unroll
  for (int i = 0; i < 4; i++) {
    int idx = tid + i * 256;              // 0..1023 : 128 rows x 8 float4
    int r = idx >> 3, g = idx & 7;
    const float4 v = *(const float4*)&A[(size_t)(row0 + r) * lda + k0 + g * 4];
    uint2 p; p.x = f2bf2(v.x, v.y); p.y = f2bf2(v.z, v.w);
    *(uint2*)&As[r * LDA_S + g * 4] = p;
  }
}

// ---- stage A tile (bf16 source) ----
__device__ __forceinline__ void stageA_bf16(const unsigned short* __restrict__ A, int lda,
                                            int row0, int k0, int tid,
                                            unsigned short* As) {
#pragma unroll
  for (int i = 0; i < 2; i++) {
    int idx = tid + i * 256;              // 0..511 : 128 rows x 4 groups of 8
    int r = idx >> 2, g = idx & 3;
    const uint4 v = *(const uint4*)&A[(size_t)(row0 + r) * lda + k0 + g * 8];
    *(uint4*)&As[r * LDA_S + g * 8] = v;
  }
}

// ---- stage B tile (fp32, row-major [k][n], ldb) transposed -> Bs[n*LDB_S + k] ----
__device__ __forceinline__ void stageB_f32(const float* __restrict__ B, int ldb,
                                           int k0, int col0, int tid,
                                           unsigned short* Bs) {
  const int kg = tid >> 5, ng = tid & 31;  // k-group of 4, n-group of 4
  float vr[4][4];
#pragma unroll
  for (int i = 0; i < 4; i++) {
    const float4 v = *(const float4*)&B[(size_t)(k0 + kg * 4 + i) * ldb + col0 + ng * 4];
    vr[i][0] = v.x; vr[i][1] = v.y; vr[i][2] = v.z; vr[i][3] = v.w;
  }
#pragma unroll
  for (int j = 0; j < 4; j++) {
    uint2 p; p.x = f2bf2(vr[0][j], vr[1][j]); p.y = f2bf2(vr[2][j], vr[3][j]);
    *(uint2*)&Bs[(ng * 4 + j) * LDB_S + kg * 4] = p;
  }
}

// ---- one BK=32 step: 4x4 tiles of 16x16x32 per wave ----
__device__ __forceinline__ void mfma_step(const unsigned short* As, const unsigned short* Bs,
                                          int wy, int wx, int l16, int quad,
                                          floatx4 acc[4][4]) {
  short8 af[4], bfr[4];
#pragma unroll
  for (int i = 0; i < 4; i++) {
    U4 t; t.u = *(const uint4*)&As[(wy * 64 + i * 16 + l16) * LDA_S + quad * 8];
    af[i] = t.s;
  }
#pragma unroll
  for (int j = 0; j < 4; j++) {
    const unsigned short* bp = &Bs[(wx * 64 + j * 16 + l16) * LDB_S + quad * 8];
    uint2 lo = *(const uint2*)bp;
    uint2 hi = *(const uint2*)(bp + 4);
    U4 t; t.u = make_uint4(lo.x, lo.y, hi.x, hi.y);
    bfr[j] = t.s;
  }
#pragma unroll
  for (int i = 0; i < 4; i++)
#pragma unroll
    for (int j = 0; j < 4; j++)
      acc[i][j] = __builtin_amdgcn_mfma_f32_16x16x32_bf16(af[i], bfr[j], acc[i][j], 0, 0, 0);
}

// ================= K1: qk = Ht @ W_qk + b_qk -> split Q,K (fp32 out) =========
__global__ __launch_bounds__(256, 2)
void k1_qk(const float* __restrict__ Ht, const float* __restrict__ Wqk,
           const float* __restrict__ bias, float* __restrict__ Q,
           float* __restrict__ Ko) {
  __shared__ unsigned short As[128 * LDA_S];
  __shared__ unsigned short Bs[128 * LDB_S];
  const int tid = threadIdx.x;
  const int row0 = blockIdx.y * 128, col0 = blockIdx.x * 128;
  const int w = tid >> 6, lane = tid & 63;
  const int wy = w >> 1, wx = w & 1, l16 = lane & 15, quad = lane >> 4;
  floatx4 acc[4][4];
#pragma unroll
  for (int i = 0; i < 4; i++)
#pragma unroll
    for (int j = 0; j < 4; j++)
#pragma unroll
      for (int r = 0; r < 4; r++) acc[i][j][r] = 0.f;

  for (int k0 = 0; k0 < TD; k0 += 32) {
    stageA_f32(Ht, TD, row0, k0, tid, As);
    stageB_f32(Wqk, 2 * TD, k0, col0, tid, Bs);
    __syncthreads();
    mfma_step(As, Bs, wy, wx, l16, quad, acc);
    __syncthreads();
  }
#pragma unroll
  for (int i = 0; i < 4; i++)
#pragma unroll
    for (int j = 0; j < 4; j++) {
      const int col = col0 + wx * 64 + j * 16 + l16;
      const float bs = bias[col];
#pragma unroll
      for (int r = 0; r < 4; r++) {
        const int row = row0 + wy * 64 + i * 16 + quad * 4 + r;
        const float v = acc[i][j][r] + bs;
        if (col < TD) Q[(size_t)row * TD + col] = v;
        else          Ko[(size_t)row * TD + (col - TD)] = v;
      }
    }
}

// ========== K2: fused scores -> softmax -> channel weights (Am, bf16) ========
__global__ __launch_bounds__(256, 2)
void k2_attn(const float* __restrict__ Q, const float* __restrict__ Kg,
             const float* __restrict__ Ml, const float* __restrict__ am,
             unsigned short* __restrict__ Am) {
  __shared__ float Ks[64][68];
  __shared__ float Qs[8][64];
  __shared__ float ams[512];
  const int b = blockIdx.y;
  const int q0 = blockIdx.x * 8;
  const int tid = threadIdx.x;
  const int w = tid >> 6, lane = tid & 63;

  for (int i = tid; i < 512; i += 256) ams[i] = am[b * 512 + i];
  __syncthreads();

  float amqv[2];
  float Mv[TNCH][2][8];
#pragma unroll
  for (int rr = 0; rr < 2; rr++) {
    const int r = w + rr * 4;
    amqv[rr] = ams[q0 + r];
#pragma unroll
    for (int i = 0; i < TNCH; i++) {
      const float* Mrow = Ml + ((size_t)((b * TNCH + i) * TS + q0 + r)) * TS;
#pragma unroll
      for (int j = 0; j < 8; j++) {
        int k = lane + 64 * j;
        Mv[i][rr][j] = Mrow[k] * ams[k] * amqv[rr];
      }
    }
  }

  float acc[TNCH][2][8];
#pragma unroll
  for (int i = 0; i < TNCH; i++)
#pragma unroll
    for (int rr = 0; rr < 2; rr++)
#pragma unroll
      for (int j = 0; j < 8; j++) acc[i][rr][j] = 0.f;

  for (int h = 0; h < TH; h++) {
    __syncthreads();
    for (int i = tid; i < 512; i += 256) {
      int r = i >> 6, d = i & 63;
      Qs[r][d] = Q[((size_t)(b * TS + q0 + r)) * TD + h * TDH + d];
    }
    float sreg[2][8];
    for (int t = 0; t < 8; t++) {
      __syncthreads();
#pragma unroll
      for (int i = 0; i < 4; i++) {
        int f4 = tid + i * 256;
        int kk = f4 >> 4, d4 = f4 & 15;
        float4 v = *(const float4*)&Kg[((size_t)(b * TS + t * TDH + kk)) * TD + h * TDH + d4 * 4];
        *(float4*)&Ks[kk][d4 * 4] = v;
      }
      __syncthreads();
      float s0 = 0.f, s1 = 0.f;
#pragma unroll
      for (int d4 = 0; d4 < 16; d4++) {
        float4 kv = *(const float4*)&Ks[lane][d4 * 4];
        float4 qa = *(const float4*)&Qs[w][d4 * 4];
        float4 qb = *(const float4*)&Qs[w + 4][d4 * 4];
        s0 += kv.x * qa.x + kv.y * qa.y + kv.z * qa.z + kv.w * qa.w;
        s1 += kv.x * qb.x + kv.y * qb.y + kv.z * qb.z + kv.w * qb.w;
      }
      int kc = t * TDH + lane;
      float mterm = (1.f - ams[kc]) * (-1e9f);
      sreg[0][t] = s0 * SCALE + mterm;
      sreg[1][t] = s1 * SCALE + mterm;
    }
#pragma unroll
    for (int rr = 0; rr < 2; rr++) {
      float mx = -3.0e38f;
#pragma unroll
      for (int j = 0; j < 8; j++) mx = fmaxf(mx, sreg[rr][j]);
#pragma unroll
      for (int off = 32; off > 0; off >>= 1) mx = fmaxf(mx, __shfl_xor(mx, off));
      float ex[8], Z = 0.f;
#pragma unroll
      for (int j = 0; j < 8; j++) { ex[j] = __expf(sreg[rr][j] - mx); Z += ex[j]; }
#pragma unroll
      for (int off = 32; off > 0; off >>= 1) Z += __shfl_xor(Z, off);
#pragma unroll
      for (int i = 0; i < TNCH; i++) {
        float dm = 0.f;
#pragma unroll
        for (int j = 0; j < 8; j++) dm += Mv[i][rr][j] * ex[j];
#pragma unroll
        for (int off = 32; off > 0; off >>= 1) dm += __shfl_xor(dm, off);
        const float winv = 1.f / (dm + 1e-10f * Z);
#pragma unroll
        for (int j = 0; j < 8; j++) acc[i][rr][j] += ex[j] * winv;
      }
    }
  }
  const float inv_h = 1.f / (float)TH;
#pragma unroll
  for (int rr = 0; rr < 2; rr++) {
    const int r = w + rr * 4;
#pragma unroll
    for (int i = 0; i < TNCH; i++) {
      unsigned short* Arow = Am + ((size_t)((i * TB + b) * TS + q0 + r)) * TS;
#pragma unroll
      for (int j = 0; j < 8; j++) {
        int k = lane + 64 * j;
        Arow[k] = f2bf(Mv[i][rr][j] * acc[i][rr][j] * inv_h);
      }
    }
  }
}

// ===== K3: G[z] = Am[z] (512x512, bf16) @ Ht[b] (512x768) -> bf16, z=ch*16+b ==
__global__ __launch_bounds__(256, 2)
void k3_feat(const unsigned short* __restrict__ Am, const float* __restrict__ Ht,
             unsigned short* __restrict__ G) {
  __shared__ unsigned short As[128 * LDA_S];
  __shared__ unsigned short Bs[128 * LDB_S];
  const int z = blockIdx.z;
  const int b = z & 15;
  const unsigned short* A = Am + (size_t)z * TS * TS;
  const float* B = Ht + (size_t)b * TS * TD;
  unsigned short* C = G + (size_t)z * TS * TD;
  const int tid = threadIdx.x;
  const int row0 = blockIdx.y * 128, col0 = blockIdx.x * 128;
  const int w = tid >> 6, lane = tid & 63;
  const int wy = w >> 1, wx = w & 1, l16 = lane & 15, quad = lane >> 4;
  floatx4 acc[4][4];
#pragma unroll
  for (int i = 0; i < 4; i++)
#pragma unroll
    for (int j = 0; j < 4; j++)
#pragma unroll
      for (int r = 0; r < 4; r++) acc[i][j][r] = 0.f;

  for (int k0 = 0; k0 < TS; k0 += 32) {
    stageA_bf16(A, TS, row0, k0, tid, As);
    stageB_f32(B, TD, k0, col0, tid, Bs);
    __syncthreads();
    mfma_step(As, Bs, wy, wx, l16, quad, acc);
    __syncthreads();
  }
#pragma unroll
  for (int i = 0; i < 4; i++)
#pragma unroll
    for (int j = 0; j < 4; j++) {
      const int col = col0 + wx * 64 + j * 16 + l16;
#pragma unroll
      for (int r = 0; r < 4; r++) {
        const int row = row0 + wy * 64 + i * 16 + quad * 4 + r;
        C[(size_t)row * TD + col] = f2bf(acc[i][j][r]);
      }
    }
}

// == K4: out = mean_ch relu(G_ch @ Wg_ch + bg_ch) * am, 3 sequential K-loops ==
__global__ __launch_bounds__(256, 2)
void k4_out(const unsigned short* __restrict__ G, const float* __restrict__ Wg,
            const float* __restrict__ bg, const float* __restrict__ am,
            float* __restrict__ out) {
  __shared__ unsigned short As[128 * LDA_S];
  __shared__ unsigned short Bs[128 * LDB_S];
  const int tid = threadIdx.x;
  const int row0 = blockIdx.y * 128, col0 = blockIdx.x * 128;
  const int w = tid >> 6, lane = tid & 63;
  const int wy = w >> 1, wx = w & 1, l16 = lane & 15, quad = lane >> 4;
  float osum[4][4][4];
#pragma unroll
  for (int i = 0; i < 4; i++)
#pragma unroll
    for (int j = 0; j < 4; j++)
#pragma unroll
      for (int r = 0; r < 4; r++) osum[i][j][r] = 0.f;

  for (int ch = 0; ch < TNCH; ch++) {
    const unsigned short* A = G + (size_t)ch * (TB * TS) * TD;
    const float* B = Wg + (size_t)ch * TD * TD;
    floatx4 acc[4][4];
#pragma unroll
    for (int i = 0; i < 4; i++)
#pragma unroll
      for (int j = 0; j < 4; j++)
#pragma unroll
        for (int r = 0; r < 4; r++) acc[i][j][r] = 0.f;

    for (int k0 = 0; k0 < TD; k0 += 32) {
      stageA_bf16(A, TD, row0, k0, tid, As);
      stageB_f32(B, TD, k0, col0, tid, Bs);
      __syncthreads();
      mfma_step(As, Bs, wy, wx, l16, quad, acc);
      __syncthreads();
    }
#pragma unroll
    for (int i = 0; i < 4; i++)
#pragma unroll
      for (int j = 0; j < 4; j++) {
        const int col = col0 + wx * 64 + j * 16 + l16;
        const float bs = bg[ch * TD + col];
#pragma unroll
        for (int r = 0; r < 4; r++)
          osum[i][j][r] += fmaxf(acc[i][j][r] + bs, 0.f);
      }
  }
#pragma unroll
  for (int i = 0; i < 4; i++)
#pragma unroll
    for (int r = 0; r < 4; r++) {
      const int row = row0 + wy * 64 + i * 16 + quad * 4 + r;
      const float amr = am[row] * (1.f / 3.f);
#pragma unroll
      for (int j = 0; j < 4; j++) {
        const int col = col0 + wx * 64 + j * 16 + l16;
        out[(size_t)row * TD + col] = osum[i][j][r] * amr;
      }
    }
}

extern "C" void kernel_launch(void* const* d_in, const int* in_sizes, int n_in,
                              void* d_out, int out_size, void* d_ws, size_t ws_size,
                              hipStream_t stream) {
  const float* Ht    = (const float*)d_in[0];
  const float* Ml    = (const float*)d_in[1];
  const float* am    = (const float*)d_in[2];
  const float* W_qk  = (const float*)d_in[3];
  const float* b_qk  = (const float*)d_in[4];
  const float* W_gat = (const float*)d_in[5];
  const float* b_gat = (const float*)d_in[6];
  float* out = (float*)d_out;
  float* ws = (float*)d_ws;

  // ws layout: Q fp32 [0, 6291456) floats; K fp32 [6291456, 12582912) floats;
  // Am bf16 at float-offset 12582912 (12.58M ushorts = 25.2 MB);
  // G bf16 overlays dead Q/K region after k2 (18.9M ushorts = 37.7 MB).
  float* Q  = ws;
  float* Kb = ws + (size_t)TB * TS * TD;
  unsigned short* Am = (unsigned short*)(ws + (size_t)2 * TB * TS * TD);
  unsigned short* G  = (unsigned short*)ws;

  k1_qk  <<<dim3(12, 64), 256, 0, stream>>>(Ht, W_qk, b_qk, Q, Kb);
  k2_attn<<<dim3(64, 16), 256, 0, stream>>>(Q, Kb, Ml, am, Am);
  k3_feat<<<dim3(6, 4, 48), 256, 0, stream>>>(Am, Ht, G);
  k4_out <<<dim3(6, 64), 256, 0, stream>>>(G, W_gat, b_gat, am, out);
}

// Round 3
// 594.651 us; speedup vs baseline: 2.6292x; 1.4035x over previous
//
#include <hip/hip_runtime.h>
#include <math.h>

typedef __attribute__((ext_vector_type(8))) short short8;
typedef __attribute__((ext_vector_type(4))) float floatx4;

#define TB 16
#define TS 512
#define TD 768
#define TH 12
#define TDH 64
#define TNCH 3

#define SCALE 0.03608439182435161f  // 1/sqrt(768)

#define LDA_S 40   // ushort stride: 32 k + 8 pad
#define LDB_S 36   // ushort stride: 32 k + 4 pad

__device__ __forceinline__ unsigned short f2bf(float f) {
  unsigned u = __float_as_uint(f);
  u += 0x7fffu + ((u >> 16) & 1u);   // round-to-nearest-even
  return (unsigned short)(u >> 16);
}
__device__ __forceinline__ unsigned f2bf2(float lo, float hi) {
  return (unsigned)f2bf(lo) | ((unsigned)f2bf(hi) << 16);
}

union U4 { uint4 u; short8 s; };

// ---- stage A tile (fp32 source) -> bf16 LDS ----
__device__ __forceinline__ void stageA_f32(const float* __restrict__ A, int lda,
                                           int row0, int k0, int tid,
                                           unsigned short* As) {
#pragma unroll
  for (int i = 0; i < 4; i++) {
    int idx = tid + i * 256;
    int r = idx >> 3, g = idx & 7;
    const float4 v = *(const float4*)&A[(size_t)(row0 + r) * lda + k0 + g * 4];
    uint2 p; p.x = f2bf2(v.x, v.y); p.y = f2bf2(v.z, v.w);
    *(uint2*)&As[r * LDA_S + g * 4] = p;
  }
}

// ---- stage A tile (bf16 source) ----
__device__ __forceinline__ void stageA_bf16(const unsigned short* __restrict__ A, int lda,
                                            int row0, int k0, int tid,
                                            unsigned short* As) {
#pragma unroll
  for (int i = 0; i < 2; i++) {
    int idx = tid + i * 256;
    int r = idx >> 2, g = idx & 3;
    const uint4 v = *(const uint4*)&A[(size_t)(row0 + r) * lda + k0 + g * 8];
    *(uint4*)&As[r * LDA_S + g * 8] = v;
  }
}

// ---- stage B tile (fp32 [k][n]) transposed -> Bs[n][k] bf16 ----
__device__ __forceinline__ void stageB_f32(const float* __restrict__ B, int ldb,
                                           int k0, int col0, int tid,
                                           unsigned short* Bs) {
  const int kg = tid >> 5, ng = tid & 31;
  float vr[4][4];
#pragma unroll
  for (int i = 0; i < 4; i++) {
    const float4 v = *(const float4*)&B[(size_t)(k0 + kg * 4 + i) * ldb + col0 + ng * 4];
    vr[i][0] = v.x; vr[i][1] = v.y; vr[i][2] = v.z; vr[i][3] = v.w;
  }
#pragma unroll
  for (int j = 0; j < 4; j++) {
    uint2 p; p.x = f2bf2(vr[0][j], vr[1][j]); p.y = f2bf2(vr[2][j], vr[3][j]);
    *(uint2*)&Bs[(ng * 4 + j) * LDB_S + kg * 4] = p;
  }
}

__device__ __forceinline__ void mfma_step(const unsigned short* As, const unsigned short* Bs,
                                          int wy, int wx, int l16, int quad,
                                          floatx4 acc[4][4]) {
  short8 af[4], bfr[4];
#pragma unroll
  for (int i = 0; i < 4; i++) {
    U4 t; t.u = *(const uint4*)&As[(wy * 64 + i * 16 + l16) * LDA_S + quad * 8];
    af[i] = t.s;
  }
#pragma unroll
  for (int j = 0; j < 4; j++) {
    const unsigned short* bp = &Bs[(wx * 64 + j * 16 + l16) * LDB_S + quad * 8];
    uint2 lo = *(const uint2*)bp;
    uint2 hi = *(const uint2*)(bp + 4);
    U4 t; t.u = make_uint4(lo.x, lo.y, hi.x, hi.y);
    bfr[j] = t.s;
  }
#pragma unroll
  for (int i = 0; i < 4; i++)
#pragma unroll
    for (int j = 0; j < 4; j++)
      acc[i][j] = __builtin_amdgcn_mfma_f32_16x16x32_bf16(af[i], bfr[j], acc[i][j], 0, 0, 0);
}

// ========= K1: qk = Ht @ W_qk + b_qk -> Q,K (bf16 out for k2 frags) =========
__global__ __launch_bounds__(256, 2)
void k1_qk(const float* __restrict__ Ht, const float* __restrict__ Wqk,
           const float* __restrict__ bias, unsigned short* __restrict__ Q,
           unsigned short* __restrict__ Ko) {
  __shared__ unsigned short As[128 * LDA_S];
  __shared__ unsigned short Bs[128 * LDB_S];
  const int tid = threadIdx.x;
  const int row0 = blockIdx.y * 128, col0 = blockIdx.x * 128;
  const int w = tid >> 6, lane = tid & 63;
  const int wy = w >> 1, wx = w & 1, l16 = lane & 15, quad = lane >> 4;
  floatx4 acc[4][4];
#pragma unroll
  for (int i = 0; i < 4; i++)
#pragma unroll
    for (int j = 0; j < 4; j++)
#pragma unroll
      for (int r = 0; r < 4; r++) acc[i][j][r] = 0.f;

  for (int k0 = 0; k0 < TD; k0 += 32) {
    stageA_f32(Ht, TD, row0, k0, tid, As);
    stageB_f32(Wqk, 2 * TD, k0, col0, tid, Bs);
    __syncthreads();
    mfma_step(As, Bs, wy, wx, l16, quad, acc);
    __syncthreads();
  }
#pragma unroll
  for (int i = 0; i < 4; i++)
#pragma unroll
    for (int j = 0; j < 4; j++) {
      const int col = col0 + wx * 64 + j * 16 + l16;
      const float bs = bias[col];
#pragma unroll
      for (int r = 0; r < 4; r++) {
        const int row = row0 + wy * 64 + i * 16 + quad * 4 + r;
        const float v = acc[i][j][r] + bs;
        if (col < TD) Q[(size_t)row * TD + col] = f2bf(v);
        else          Ko[(size_t)row * TD + (col - TD)] = f2bf(v);
      }
    }
}

// ==== K2: MFMA scores from global bf16 frags; softmax + channel weights ====
// Block: 16 q-rows of batch b, all 512 k. Wave w owns k-quarter w*128.
// Per lane: C-layout rows quad*4+r (r<4), cols kbase + kt*16 + l16 (kt<8).
__global__ __launch_bounds__(256, 2)
void k2_attn(const unsigned short* __restrict__ Q, const unsigned short* __restrict__ Kb,
             const float* __restrict__ Ml, const float* __restrict__ am,
             unsigned short* __restrict__ Am) {
  __shared__ float smx[16][4];
  __shared__ float4 szd[16][4];
  const int b = blockIdx.y;
  const int q0 = blockIdx.x * 16;
  const int tid = threadIdx.x;
  const int w = tid >> 6, lane = tid & 63;
  const int l16 = lane & 15, quad = lane >> 4;
  const int kbase = w * 128;

  const float* amb = am + b * TS;
  float amq[4], amk[8], maskv[8];
#pragma unroll
  for (int r = 0; r < 4; r++) amq[r] = amb[q0 + quad * 4 + r];
#pragma unroll
  for (int kt = 0; kt < 8; kt++) {
    amk[kt] = amb[kbase + kt * 16 + l16];
    maskv[kt] = (1.f - amk[kt]) * (-1e9f);
  }

  // M, mask-premultiplied, bf16-packed over kt pairs: Mpk[ch][r][kt>>1]
  unsigned Mpk[TNCH][4][4];
#pragma unroll
  for (int i = 0; i < TNCH; i++)
#pragma unroll
    for (int r = 0; r < 4; r++) {
      const float* Mrow = Ml + ((size_t)((b * TNCH + i) * TS + q0 + quad * 4 + r)) * TS;
#pragma unroll
      for (int kt2 = 0; kt2 < 4; kt2++) {
        const int ke = kbase + kt2 * 32 + l16;
        const float me = Mrow[ke] * amk[kt2 * 2] * amq[r];
        const float mo = Mrow[ke + 16] * amk[kt2 * 2 + 1] * amq[r];
        Mpk[i][r][kt2] = f2bf2(me, mo);
      }
    }

  float acc[TNCH][8][4];
#pragma unroll
  for (int i = 0; i < TNCH; i++)
#pragma unroll
    for (int kt = 0; kt < 8; kt++)
#pragma unroll
      for (int r = 0; r < 4; r++) acc[i][kt][r] = 0.f;

  const unsigned short* qbase = Q + ((size_t)(b * TS + q0 + l16)) * TD + quad * 8;
  const unsigned short* kb0   = Kb + ((size_t)(b * TS + kbase + l16)) * TD + quad * 8;

  for (int h = 0; h < TH; h++) {
    // ---- scores via MFMA, frags straight from global (L2-hot) ----
    floatx4 sacc[8];
#pragma unroll
    for (int kt = 0; kt < 8; kt++)
#pragma unroll
      for (int r = 0; r < 4; r++) sacc[kt][r] = 0.f;
#pragma unroll
    for (int dk = 0; dk < 2; dk++) {
      U4 a; a.u = *(const uint4*)(qbase + h * TDH + dk * 32);
#pragma unroll
      for (int kt = 0; kt < 8; kt++) {
        U4 bb; bb.u = *(const uint4*)(kb0 + (size_t)kt * 16 * TD + h * TDH + dk * 32);
        sacc[kt] = __builtin_amdgcn_mfma_f32_16x16x32_bf16(a.s, bb.s, sacc[kt], 0, 0, 0);
      }
    }
    float s[8][4];
#pragma unroll
    for (int kt = 0; kt < 8; kt++)
#pragma unroll
      for (int r = 0; r < 4; r++) s[kt][r] = sacc[kt][r] * SCALE + maskv[kt];

    // ---- row max: intra-wave (16-lane quad group) then cross-wave via LDS ----
    float mxp[4];
#pragma unroll
    for (int r = 0; r < 4; r++) {
      float m = s[0][r];
#pragma unroll
      for (int kt = 1; kt < 8; kt++) m = fmaxf(m, s[kt][r]);
#pragma unroll
      for (int off = 1; off < 16; off <<= 1) m = fmaxf(m, __shfl_xor(m, off));
      mxp[r] = m;
    }
    if (l16 == 0) {
#pragma unroll
      for (int r = 0; r < 4; r++) smx[quad * 4 + r][w] = mxp[r];
    }
    __syncthreads();
    float mxg[4];
#pragma unroll
    for (int r = 0; r < 4; r++) {
      float4 t = *(const float4*)smx[quad * 4 + r];
      mxg[r] = fmaxf(fmaxf(t.x, t.y), fmaxf(t.z, t.w));
    }

    // ---- ex, partial Z and per-channel dm ----
    float Zp[4] = {0.f, 0.f, 0.f, 0.f};
#pragma unroll
    for (int kt = 0; kt < 8; kt++)
#pragma unroll
      for (int r = 0; r < 4; r++) {
        float e = __expf(s[kt][r] - mxg[r]);
        s[kt][r] = e;
        Zp[r] += e;
      }
    float dmp[TNCH][4];
#pragma unroll
    for (int i = 0; i < TNCH; i++)
#pragma unroll
      for (int r = 0; r < 4; r++) {
        float d = 0.f;
#pragma unroll
        for (int kt2 = 0; kt2 < 4; kt2++) {
          unsigned u = Mpk[i][r][kt2];
          d += __uint_as_float(u << 16) * s[kt2 * 2][r];
          d += __uint_as_float(u & 0xffff0000u) * s[kt2 * 2 + 1][r];
        }
        dmp[i][r] = d;
      }
#pragma unroll
    for (int r = 0; r < 4; r++) {
#pragma unroll
      for (int off = 1; off < 16; off <<= 1) {
        Zp[r] += __shfl_xor(Zp[r], off);
        dmp[0][r] += __shfl_xor(dmp[0][r], off);
        dmp[1][r] += __shfl_xor(dmp[1][r], off);
        dmp[2][r] += __shfl_xor(dmp[2][r], off);
      }
    }
    if (l16 == 0) {
#pragma unroll
      for (int r = 0; r < 4; r++)
        szd[quad * 4 + r][w] = make_float4(Zp[r], dmp[0][r], dmp[1][r], dmp[2][r]);
    }
    __syncthreads();
#pragma unroll
    for (int r = 0; r < 4; r++) {
      float4 t0 = szd[quad * 4 + r][0];
      float4 t1 = szd[quad * 4 + r][1];
      float4 t2 = szd[quad * 4 + r][2];
      float4 t3 = szd[quad * 4 + r][3];
      const float Z  = t0.x + t1.x + t2.x + t3.x;
      const float w0 = 1.f / (t0.y + t1.y + t2.y + t3.y + 1e-10f * Z);
      const float w1 = 1.f / (t0.z + t1.z + t2.z + t3.z + 1e-10f * Z);
      const float w2 = 1.f / (t0.w + t1.w + t2.w + t3.w + 1e-10f * Z);
#pragma unroll
      for (int kt = 0; kt < 8; kt++) {
        acc[0][kt][r] += s[kt][r] * w0;
        acc[1][kt][r] += s[kt][r] * w1;
        acc[2][kt][r] += s[kt][r] * w2;
      }
    }
  }

  // ---- output: fresh fp32 M (exact), bf16 store ----
  const float inv_h = 1.f / (float)TH;
#pragma unroll
  for (int i = 0; i < TNCH; i++)
#pragma unroll
    for (int r = 0; r < 4; r++) {
      const int q = q0 + quad * 4 + r;
      const float* Mrow = Ml + ((size_t)((b * TNCH + i) * TS + q)) * TS;
      unsigned short* Arow = Am + ((size_t)((i * TB + b) * TS + q)) * TS;
#pragma unroll
      for (int kt = 0; kt < 8; kt++) {
        const int k = kbase + kt * 16 + l16;
        const float mv = Mrow[k] * amk[kt] * amq[r];
        Arow[k] = f2bf(mv * acc[i][kt][r] * inv_h);
      }
    }
}

// ===== K3: G[z] = Am[z] (512x512 bf16) @ Ht[b] (512x768 f32) -> bf16 =====
__global__ __launch_bounds__(256, 2)
void k3_feat(const unsigned short* __restrict__ Am, const float* __restrict__ Ht,
             unsigned short* __restrict__ G) {
  __shared__ unsigned short As[128 * LDA_S];
  __shared__ unsigned short Bs[128 * LDB_S];
  const int z = blockIdx.z;
  const int b = z & 15;
  const unsigned short* A = Am + (size_t)z * TS * TS;
  const float* B = Ht + (size_t)b * TS * TD;
  unsigned short* C = G + (size_t)z * TS * TD;
  const int tid = threadIdx.x;
  const int row0 = blockIdx.y * 128, col0 = blockIdx.x * 128;
  const int w = tid >> 6, lane = tid & 63;
  const int wy = w >> 1, wx = w & 1, l16 = lane & 15, quad = lane >> 4;
  floatx4 acc[4][4];
#pragma unroll
  for (int i = 0; i < 4; i++)
#pragma unroll
    for (int j = 0; j < 4; j++)
#pragma unroll
      for (int r = 0; r < 4; r++) acc[i][j][r] = 0.f;

  for (int k0 = 0; k0 < TS; k0 += 32) {
    stageA_bf16(A, TS, row0, k0, tid, As);
    stageB_f32(B, TD, k0, col0, tid, Bs);
    __syncthreads();
    mfma_step(As, Bs, wy, wx, l16, quad, acc);
    __syncthreads();
  }
#pragma unroll
  for (int i = 0; i < 4; i++)
#pragma unroll
    for (int j = 0; j < 4; j++) {
      const int col = col0 + wx * 64 + j * 16 + l16;
#pragma unroll
      for (int r = 0; r < 4; r++) {
        const int row = row0 + wy * 64 + i * 16 + quad * 4 + r;
        C[(size_t)row * TD + col] = f2bf(acc[i][j][r]);
      }
    }
}

// == K4: out = mean_ch relu(G_ch @ Wg_ch + bg_ch) * am ==
__global__ __launch_bounds__(256, 2)
void k4_out(const unsigned short* __restrict__ G, const float* __restrict__ Wg,
            const float* __restrict__ bg, const float* __restrict__ am,
            float* __restrict__ out) {
  __shared__ unsigned short As[128 * LDA_S];
  __shared__ unsigned short Bs[128 * LDB_S];
  const int tid = threadIdx.x;
  const int row0 = blockIdx.y * 128, col0 = blockIdx.x * 128;
  const int w = tid >> 6, lane = tid & 63;
  const int wy = w >> 1, wx = w & 1, l16 = lane & 15, quad = lane >> 4;
  float osum[4][4][4];
#pragma unroll
  for (int i = 0; i < 4; i++)
#pragma unroll
    for (int j = 0; j < 4; j++)
#pragma unroll
      for (int r = 0; r < 4; r++) osum[i][j][r] = 0.f;

  for (int ch = 0; ch < TNCH; ch++) {
    const unsigned short* A = G + (size_t)ch * (TB * TS) * TD;
    const float* B = Wg + (size_t)ch * TD * TD;
    floatx4 acc[4][4];
#pragma unroll
    for (int i = 0; i < 4; i++)
#pragma unroll
      for (int j = 0; j < 4; j++)
#pragma unroll
        for (int r = 0; r < 4; r++) acc[i][j][r] = 0.f;

    for (int k0 = 0; k0 < TD; k0 += 32) {
      stageA_bf16(A, TD, row0, k0, tid, As);
      stageB_f32(B, TD, k0, col0, tid, Bs);
      __syncthreads();
      mfma_step(As, Bs, wy, wx, l16, quad, acc);
      __syncthreads();
    }
#pragma unroll
    for (int i = 0; i < 4; i++)
#pragma unroll
      for (int j = 0; j < 4; j++) {
        const int col = col0 + wx * 64 + j * 16 + l16;
        const float bs = bg[ch * TD + col];
#pragma unroll
        for (int r = 0; r < 4; r++)
          osum[i][j][r] += fmaxf(acc[i][j][r] + bs, 0.f);
      }
  }
#pragma unroll
  for (int i = 0; i < 4; i++)
#pragma unroll
    for (int r = 0; r < 4; r++) {
      const int row = row0 + wy * 64 + i * 16 + quad * 4 + r;
      const float amr = am[row] * (1.f / 3.f);
#pragma unroll
      for (int j = 0; j < 4; j++) {
        const int col = col0 + wx * 64 + j * 16 + l16;
        out[(size_t)row * TD + col] = osum[i][j][r] * amr;
      }
    }
}

extern "C" void kernel_launch(void* const* d_in, const int* in_sizes, int n_in,
                              void* d_out, int out_size, void* d_ws, size_t ws_size,
                              hipStream_t stream) {
  const float* Ht    = (const float*)d_in[0];
  const float* Ml    = (const float*)d_in[1];
  const float* am    = (const float*)d_in[2];
  const float* W_qk  = (const float*)d_in[3];
  const float* b_qk  = (const float*)d_in[4];
  const float* W_gat = (const float*)d_in[5];
  const float* b_gat = (const float*)d_in[6];
  float* out = (float*)d_out;

  // ws layout (ushorts): Q[0,6291456) K[...,12582912) Am[...,25165824)
  //                      G[25165824, 44040192)  -> 88 MB total
  unsigned short* base = (unsigned short*)d_ws;
  unsigned short* Q  = base;
  unsigned short* Kw = base + (size_t)TB * TS * TD;
  unsigned short* Am = base + (size_t)2 * TB * TS * TD;
  unsigned short* G  = base + (size_t)2 * TB * TS * TD + (size_t)TNCH * TB * TS * TS;

  k1_qk  <<<dim3(12, 64), 256, 0, stream>>>(Ht, W_qk, b_qk, Q, Kw);
  k2_attn<<<dim3(32, 16), 256, 0, stream>>>(Q, Kw, Ml, am, Am);
  k3_feat<<<dim3(6, 4, 48), 256, 0, stream>>>(Am, Ht, G);
  k4_out <<<dim3(6, 64), 256, 0, stream>>>(G, W_gat, b_gat, am, out);
}

// Round 5
// 581.871 us; speedup vs baseline: 2.6870x; 1.0220x over previous
//
#include <hip/hip_runtime.h>
#include <math.h>

typedef __attribute__((ext_vector_type(8))) short short8;
typedef __attribute__((ext_vector_type(4))) float floatx4;

#define TB 16
#define TS 512
#define TD 768
#define TH 12
#define TDH 64
#define TNCH 3

#define SCALE 0.03608439182435161f  // 1/sqrt(768)

#define LDA_S 40   // ushort stride: 32 k + 8 pad
#define LDB_S 36   // ushort stride: 32 k + 4 pad

__device__ __forceinline__ unsigned short f2bf(float f) {
  unsigned u = __float_as_uint(f);
  u += 0x7fffu + ((u >> 16) & 1u);   // round-to-nearest-even
  return (unsigned short)(u >> 16);
}
__device__ __forceinline__ unsigned f2bf2(float lo, float hi) {
  return (unsigned)f2bf(lo) | ((unsigned)f2bf(hi) << 16);
}

union U4 { uint4 u; short8 s; };

// ---- stage A tile (fp32 source) -> bf16 LDS ----
__device__ __forceinline__ void stageA_f32(const float* __restrict__ A, int lda,
                                           int row0, int k0, int tid,
                                           unsigned short* As) {
#pragma unroll
  for (int i = 0; i < 4; i++) {
    int idx = tid + i * 256;
    int r = idx >> 3, g = idx & 7;
    const float4 v = *(const float4*)&A[(size_t)(row0 + r) * lda + k0 + g * 4];
    uint2 p; p.x = f2bf2(v.x, v.y); p.y = f2bf2(v.z, v.w);
    *(uint2*)&As[r * LDA_S + g * 4] = p;
  }
}

// ---- stage A tile (bf16 source) ----
__device__ __forceinline__ void stageA_bf16(const unsigned short* __restrict__ A, int lda,
                                            int row0, int k0, int tid,
                                            unsigned short* As) {
#pragma unroll
  for (int i = 0; i < 2; i++) {
    int idx = tid + i * 256;
    int r = idx >> 2, g = idx & 3;
    const uint4 v = *(const uint4*)&A[(size_t)(row0 + r) * lda + k0 + g * 8];
    *(uint4*)&As[r * LDA_S + g * 8] = v;
  }
}

// ---- stage B tile (fp32 [k][n]) transposed -> Bs[n][k] bf16 ----
__device__ __forceinline__ void stageB_f32(const float* __restrict__ B, int ldb,
                                           int k0, int col0, int tid,
                                           unsigned short* Bs) {
  const int kg = tid >> 5, ng = tid & 31;
  float vr[4][4];
#pragma unroll
  for (int i = 0; i < 4; i++) {
    const float4 v = *(const float4*)&B[(size_t)(k0 + kg * 4 + i) * ldb + col0 + ng * 4];
    vr[i][0] = v.x; vr[i][1] = v.y; vr[i][2] = v.z; vr[i][3] = v.w;
  }
#pragma unroll
  for (int j = 0; j < 4; j++) {
    uint2 p; p.x = f2bf2(vr[0][j], vr[1][j]); p.y = f2bf2(vr[2][j], vr[3][j]);
    *(uint2*)&Bs[(ng * 4 + j) * LDB_S + kg * 4] = p;
  }
}

__device__ __forceinline__ void mfma_step(const unsigned short* As, const unsigned short* Bs,
                                          int wy, int wx, int l16, int quad,
                                          floatx4 acc[4][4]) {
  short8 af[4], bfr[4];
#pragma unroll
  for (int i = 0; i < 4; i++) {
    U4 t; t.u = *(const uint4*)&As[(wy * 64 + i * 16 + l16) * LDA_S + quad * 8];
    af[i] = t.s;
  }
#pragma unroll
  for (int j = 0; j < 4; j++) {
    const unsigned short* bp = &Bs[(wx * 64 + j * 16 + l16) * LDB_S + quad * 8];
    uint2 lo = *(const uint2*)bp;
    uint2 hi = *(const uint2*)(bp + 4);
    U4 t; t.u = make_uint4(lo.x, lo.y, hi.x, hi.y);
    bfr[j] = t.s;
  }
#pragma unroll
  for (int i = 0; i < 4; i++)
#pragma unroll
    for (int j = 0; j < 4; j++)
      acc[i][j] = __builtin_amdgcn_mfma_f32_16x16x32_bf16(af[i], bfr[j], acc[i][j], 0, 0, 0);
}

// ========= K1: qk = Ht @ W_qk + b_qk -> Q,K (bf16 out) =========
__global__ __launch_bounds__(256, 2)
void k1_qk(const float* __restrict__ Ht, const float* __restrict__ Wqk,
           const float* __restrict__ bias, unsigned short* __restrict__ Q,
           unsigned short* __restrict__ Ko) {
  __shared__ unsigned short As[128 * LDA_S];
  __shared__ unsigned short Bs[128 * LDB_S];
  const int tid = threadIdx.x;
  const int row0 = blockIdx.y * 128, col0 = blockIdx.x * 128;
  const int w = tid >> 6, lane = tid & 63;
  const int wy = w >> 1, wx = w & 1, l16 = lane & 15, quad = lane >> 4;
  floatx4 acc[4][4];
#pragma unroll
  for (int i = 0; i < 4; i++)
#pragma unroll
    for (int j = 0; j < 4; j++)
#pragma unroll
      for (int r = 0; r < 4; r++) acc[i][j][r] = 0.f;

  for (int k0 = 0; k0 < TD; k0 += 32) {
    stageA_f32(Ht, TD, row0, k0, tid, As);
    stageB_f32(Wqk, 2 * TD, k0, col0, tid, Bs);
    __syncthreads();
    mfma_step(As, Bs, wy, wx, l16, quad, acc);
    __syncthreads();
  }
#pragma unroll
  for (int i = 0; i < 4; i++)
#pragma unroll
    for (int j = 0; j < 4; j++) {
      const int col = col0 + wx * 64 + j * 16 + l16;
      const float bs = bias[col];
#pragma unroll
      for (int r = 0; r < 4; r++) {
        const int row = row0 + wy * 64 + i * 16 + quad * 4 + r;
        const float v = acc[i][j][r] + bs;
        if (col < TD) Q[(size_t)row * TD + col] = f2bf(v);
        else          Ko[(size_t)row * TD + (col - TD)] = f2bf(v);
      }
    }
}

// ==== K2: MFMA scores from global bf16 frags; softmax + channel weights ====
// Grid 512 linear, XCD-affinity swizzle: all 32 blocks of batch b on XCD b&7.
// Block: 16 q-rows, all 512 k; wave w owns k-quarter w*128.
// Output: fresh fp32 M numerator (R3-exact values); per-lane 16-bit obuf
// stores (no shfl pairing), then uint4 copy-out for full-line global writes.
#define OB_S 520   // obuf row stride (bf16): 512 + 8 pad
__global__ __launch_bounds__(256, 2)
void k2_attn(const unsigned short* __restrict__ Q, const unsigned short* __restrict__ Kb,
             const float* __restrict__ Ml, const float* __restrict__ am,
             unsigned short* __restrict__ Am) {
  __shared__ float smx[16][4];
  __shared__ float4 szd[16][4];
  __shared__ unsigned short obuf[16 * OB_S];
  const int i0 = blockIdx.x;
  const int xcd = i0 & 7, jj = i0 >> 3;
  const int b = xcd + 8 * (jj & 1);
  const int q0 = (jj >> 1) * 16;
  const int tid = threadIdx.x;
  const int w = tid >> 6, lane = tid & 63;
  const int l16 = lane & 15, quad = lane >> 4;
  const int kbase = w * 128;

  const float* amb = am + b * TS;
  float amq[4], amk[8], maskv[8];
#pragma unroll
  for (int r = 0; r < 4; r++) amq[r] = amb[q0 + quad * 4 + r];
#pragma unroll
  for (int kt = 0; kt < 8; kt++) {
    amk[kt] = amb[kbase + kt * 16 + l16];
    maskv[kt] = (1.f - amk[kt]) * (-1e9f);
  }

  // M, mask-premultiplied, bf16-packed over kt pairs: Mpk[ch][r][kt>>1]
  // (used ONLY inside dm, where bf16 error averages out — R3-validated)
  unsigned Mpk[TNCH][4][4];
#pragma unroll
  for (int i = 0; i < TNCH; i++)
#pragma unroll
    for (int r = 0; r < 4; r++) {
      const float* Mrow = Ml + ((size_t)((b * TNCH + i) * TS + q0 + quad * 4 + r)) * TS;
#pragma unroll
      for (int kt2 = 0; kt2 < 4; kt2++) {
        const int ke = kbase + kt2 * 32 + l16;
        const float me = Mrow[ke] * amk[kt2 * 2] * amq[r];
        const float mo = Mrow[ke + 16] * amk[kt2 * 2 + 1] * amq[r];
        Mpk[i][r][kt2] = f2bf2(me, mo);
      }
    }

  float acc[TNCH][8][4];
#pragma unroll
  for (int i = 0; i < TNCH; i++)
#pragma unroll
    for (int kt = 0; kt < 8; kt++)
#pragma unroll
      for (int r = 0; r < 4; r++) acc[i][kt][r] = 0.f;

  const unsigned short* qbase = Q + ((size_t)(b * TS + q0 + l16)) * TD + quad * 8;
  const unsigned short* kb0   = Kb + ((size_t)(b * TS + kbase + l16)) * TD + quad * 8;

  for (int h = 0; h < TH; h++) {
    floatx4 sacc[8];
#pragma unroll
    for (int kt = 0; kt < 8; kt++)
#pragma unroll
      for (int r = 0; r < 4; r++) sacc[kt][r] = 0.f;
#pragma unroll
    for (int dk = 0; dk < 2; dk++) {
      U4 a; a.u = *(const uint4*)(qbase + h * TDH + dk * 32);
#pragma unroll
      for (int kt = 0; kt < 8; kt++) {
        U4 bb; bb.u = *(const uint4*)(kb0 + (size_t)kt * 16 * TD + h * TDH + dk * 32);
        sacc[kt] = __builtin_amdgcn_mfma_f32_16x16x32_bf16(a.s, bb.s, sacc[kt], 0, 0, 0);
      }
    }
    float s[8][4];
#pragma unroll
    for (int kt = 0; kt < 8; kt++)
#pragma unroll
      for (int r = 0; r < 4; r++) s[kt][r] = sacc[kt][r] * SCALE + maskv[kt];

    // row max: intra-quad-group shfl, then cross-wave via LDS
    float mxp[4];
#pragma unroll
    for (int r = 0; r < 4; r++) {
      float m = s[0][r];
#pragma unroll
      for (int kt = 1; kt < 8; kt++) m = fmaxf(m, s[kt][r]);
#pragma unroll
      for (int off = 1; off < 16; off <<= 1) m = fmaxf(m, __shfl_xor(m, off));
      mxp[r] = m;
    }
    if (l16 == 0) {
#pragma unroll
      for (int r = 0; r < 4; r++) smx[quad * 4 + r][w] = mxp[r];
    }
    __syncthreads();
    float mxg[4];
#pragma unroll
    for (int r = 0; r < 4; r++) {
      float4 t = *(const float4*)smx[quad * 4 + r];
      mxg[r] = fmaxf(fmaxf(t.x, t.y), fmaxf(t.z, t.w));
    }

    float Zp[4] = {0.f, 0.f, 0.f, 0.f};
#pragma unroll
    for (int kt = 0; kt < 8; kt++)
#pragma unroll
      for (int r = 0; r < 4; r++) {
        float e = __expf(s[kt][r] - mxg[r]);
        s[kt][r] = e;
        Zp[r] += e;
      }
    float dmp[TNCH][4];
#pragma unroll
    for (int i = 0; i < TNCH; i++)
#pragma unroll
      for (int r = 0; r < 4; r++) {
        float d = 0.f;
#pragma unroll
        for (int kt2 = 0; kt2 < 4; kt2++) {
          unsigned u = Mpk[i][r][kt2];
          d += __uint_as_float(u << 16) * s[kt2 * 2][r];
          d += __uint_as_float(u & 0xffff0000u) * s[kt2 * 2 + 1][r];
        }
        dmp[i][r] = d;
      }
#pragma unroll
    for (int r = 0; r < 4; r++) {
#pragma unroll
      for (int off = 1; off < 16; off <<= 1) {
        Zp[r] += __shfl_xor(Zp[r], off);
        dmp[0][r] += __shfl_xor(dmp[0][r], off);
        dmp[1][r] += __shfl_xor(dmp[1][r], off);
        dmp[2][r] += __shfl_xor(dmp[2][r], off);
      }
    }
    if (l16 == 0) {
#pragma unroll
      for (int r = 0; r < 4; r++)
        szd[quad * 4 + r][w] = make_float4(Zp[r], dmp[0][r], dmp[1][r], dmp[2][r]);
    }
    __syncthreads();
#pragma unroll
    for (int r = 0; r < 4; r++) {
      float4 t0 = szd[quad * 4 + r][0];
      float4 t1 = szd[quad * 4 + r][1];
      float4 t2 = szd[quad * 4 + r][2];
      float4 t3 = szd[quad * 4 + r][3];
      const float Z  = t0.x + t1.x + t2.x + t3.x;
      const float w0 = 1.f / (t0.y + t1.y + t2.y + t3.y + 1e-10f * Z);
      const float w1 = 1.f / (t0.z + t1.z + t2.z + t3.z + 1e-10f * Z);
      const float w2 = 1.f / (t0.w + t1.w + t2.w + t3.w + 1e-10f * Z);
#pragma unroll
      for (int kt = 0; kt < 8; kt++) {
        acc[0][kt][r] += s[kt][r] * w0;
        acc[1][kt][r] += s[kt][r] * w1;
        acc[2][kt][r] += s[kt][r] * w2;
      }
    }
  }

  // ---- output: fresh fp32 M numerator (R3-exact), per-lane b16 obuf store,
  //      then full-line uint4 copy-out ----
  const float inv_h = 1.f / (float)TH;
  for (int i = 0; i < TNCH; i++) {
#pragma unroll
    for (int r = 0; r < 4; r++) {
      const int q = q0 + quad * 4 + r;
      const float* Mrow = Ml + ((size_t)((b * TNCH + i) * TS + q)) * TS;
#pragma unroll
      for (int kt = 0; kt < 8; kt++) {
        const int k = kbase + kt * 16 + l16;
        const float mv = Mrow[k] * amk[kt] * amq[r];
        obuf[(quad * 4 + r) * OB_S + k] = f2bf(mv * acc[i][kt][r] * inv_h);
      }
    }
    __syncthreads();
#pragma unroll
    for (int it = 0; it < 4; it++) {
      const int idx = tid + it * 256;             // 0..1023 = 16 rows x 64 uint4
      const int row = idx >> 6, c16 = idx & 63;
      const uint4 v = *(const uint4*)&obuf[row * OB_S + c16 * 8];
      *(uint4*)&Am[((size_t)((i * TB + b) * TS + q0 + row)) * TS + c16 * 8] = v;
    }
    __syncthreads();
  }
}

// ===== K3: G[z] = Am[z] (512x512 bf16) @ Ht[b] (512x768 f32) -> bf16 =====
__global__ __launch_bounds__(256, 2)
void k3_feat(const unsigned short* __restrict__ Am, const float* __restrict__ Ht,
             unsigned short* __restrict__ G) {
  __shared__ unsigned short As[128 * LDA_S];
  __shared__ unsigned short Bs[128 * LDB_S];
  const int z = blockIdx.z;
  const int b = z & 15;
  const unsigned short* A = Am + (size_t)z * TS * TS;
  const float* B = Ht + (size_t)b * TS * TD;
  unsigned short* C = G + (size_t)z * TS * TD;
  const int tid = threadIdx.x;
  const int row0 = blockIdx.y * 128, col0 = blockIdx.x * 128;
  const int w = tid >> 6, lane = tid & 63;
  const int wy = w >> 1, wx = w & 1, l16 = lane & 15, quad = lane >> 4;
  floatx4 acc[4][4];
#pragma unroll
  for (int i = 0; i < 4; i++)
#pragma unroll
    for (int j = 0; j < 4; j++)
#pragma unroll
      for (int r = 0; r < 4; r++) acc[i][j][r] = 0.f;

  for (int k0 = 0; k0 < TS; k0 += 32) {
    stageA_bf16(A, TS, row0, k0, tid, As);
    stageB_f32(B, TD, k0, col0, tid, Bs);
    __syncthreads();
    mfma_step(As, Bs, wy, wx, l16, quad, acc);
    __syncthreads();
  }
#pragma unroll
  for (int i = 0; i < 4; i++)
#pragma unroll
    for (int j = 0; j < 4; j++) {
      const int col = col0 + wx * 64 + j * 16 + l16;
#pragma unroll
      for (int r = 0; r < 4; r++) {
        const int row = row0 + wy * 64 + i * 16 + quad * 4 + r;
        C[(size_t)row * TD + col] = f2bf(acc[i][j][r]);
      }
    }
}

// == K4: out = mean_ch relu(G_ch @ Wg_ch + bg_ch) * am ==
__global__ __launch_bounds__(256, 2)
void k4_out(const unsigned short* __restrict__ G, const float* __restrict__ Wg,
            const float* __restrict__ bg, const float* __restrict__ am,
            float* __restrict__ out) {
  __shared__ unsigned short As[128 * LDA_S];
  __shared__ unsigned short Bs[128 * LDB_S];
  const int tid = threadIdx.x;
  const int row0 = blockIdx.y * 128, col0 = blockIdx.x * 128;
  const int w = tid >> 6, lane = tid & 63;
  const int wy = w >> 1, wx = w & 1, l16 = lane & 15, quad = lane >> 4;
  float osum[4][4][4];
#pragma unroll
  for (int i = 0; i < 4; i++)
#pragma unroll
    for (int j = 0; j < 4; j++)
#pragma unroll
      for (int r = 0; r < 4; r++) osum[i][j][r] = 0.f;

  for (int ch = 0; ch < TNCH; ch++) {
    const unsigned short* A = G + (size_t)ch * (TB * TS) * TD;
    const float* B = Wg + (size_t)ch * TD * TD;
    floatx4 acc[4][4];
#pragma unroll
    for (int i = 0; i < 4; i++)
#pragma unroll
      for (int j = 0; j < 4; j++)
#pragma unroll
        for (int r = 0; r < 4; r++) acc[i][j][r] = 0.f;

    for (int k0 = 0; k0 < TD; k0 += 32) {
      stageA_bf16(A, TD, row0, k0, tid, As);
      stageB_f32(B, TD, k0, col0, tid, Bs);
      __syncthreads();
      mfma_step(As, Bs, wy, wx, l16, quad, acc);
      __syncthreads();
    }
#pragma unroll
    for (int i = 0; i < 4; i++)
#pragma unroll
      for (int j = 0; j < 4; j++) {
        const int col = col0 + wx * 64 + j * 16 + l16;
        const float bs = bg[ch * TD + col];
#pragma unroll
        for (int r = 0; r < 4; r++)
          osum[i][j][r] += fmaxf(acc[i][j][r] + bs, 0.f);
      }
  }
#pragma unroll
  for (int i = 0; i < 4; i++)
#pragma unroll
    for (int r = 0; r < 4; r++) {
      const int row = row0 + wy * 64 + i * 16 + quad * 4 + r;
      const float amr = am[row] * (1.f / 3.f);
#pragma unroll
      for (int j = 0; j < 4; j++) {
        const int col = col0 + wx * 64 + j * 16 + l16;
        out[(size_t)row * TD + col] = osum[i][j][r] * amr;
      }
    }
}

extern "C" void kernel_launch(void* const* d_in, const int* in_sizes, int n_in,
                              void* d_out, int out_size, void* d_ws, size_t ws_size,
                              hipStream_t stream) {
  const float* Ht    = (const float*)d_in[0];
  const float* Ml    = (const float*)d_in[1];
  const float* am    = (const float*)d_in[2];
  const float* W_qk  = (const float*)d_in[3];
  const float* b_qk  = (const float*)d_in[4];
  const float* W_gat = (const float*)d_in[5];
  const float* b_gat = (const float*)d_in[6];
  float* out = (float*)d_out;

  // ws layout (ushorts): Q[0,6291456) K[...,12582912) Am[...,25165824)
  //                      G[25165824, 44040192)  -> 88 MB total
  unsigned short* base = (unsigned short*)d_ws;
  unsigned short* Q  = base;
  unsigned short* Kw = base + (size_t)TB * TS * TD;
  unsigned short* Am = base + (size_t)2 * TB * TS * TD;
  unsigned short* G  = base + (size_t)2 * TB * TS * TD + (size_t)TNCH * TB * TS * TS;

  k1_qk  <<<dim3(12, 64), 256, 0, stream>>>(Ht, W_qk, b_qk, Q, Kw);
  k2_attn<<<dim3(512), 256, 0, stream>>>(Q, Kw, Ml, am, Am);
  k3_feat<<<dim3(6, 4, 48), 256, 0, stream>>>(Am, Ht, G);
  k4_out <<<dim3(6, 64), 256, 0, stream>>>(G, W_gat, b_gat, am, out);
}

// Round 6
// 521.441 us; speedup vs baseline: 2.9984x; 1.1159x over previous
//
#include <hip/hip_runtime.h>
#include <math.h>

typedef __attribute__((ext_vector_type(8))) short short8;
typedef __attribute__((ext_vector_type(4))) float floatx4;

#define TB 16
#define TS 512
#define TD 768
#define TH 12
#define TDH 64
#define TNCH 3

#define SCALE 0.03608439182435161f  // 1/sqrt(768)

#define LDA_S 40   // ushort stride: 32 k + 8 pad
#define LDB_S 36   // ushort stride: 32 k + 4 pad

__device__ __forceinline__ unsigned short f2bf(float f) {
  unsigned u = __float_as_uint(f);
  u += 0x7fffu + ((u >> 16) & 1u);   // round-to-nearest-even
  return (unsigned short)(u >> 16);
}
__device__ __forceinline__ unsigned f2bf2(float lo, float hi) {
  return (unsigned)f2bf(lo) | ((unsigned)f2bf(hi) << 16);
}

union U4 { uint4 u; short8 s; };

// ===================== prep kernels (one-shot convert/transpose) ============
// pconv: fp32 -> bf16, contiguous, 8 els/thread
__global__ __launch_bounds__(256)
void pconv(const float* __restrict__ src, unsigned short* __restrict__ dst) {
  const int i = (blockIdx.x * 256 + threadIdx.x) * 8;
  const float4 a = *(const float4*)&src[i];
  const float4 b = *(const float4*)&src[i + 4];
  uint4 o;
  o.x = f2bf2(a.x, a.y); o.y = f2bf2(a.z, a.w);
  o.z = f2bf2(b.x, b.y); o.w = f2bf2(b.z, b.w);
  *(uint4*)&dst[i] = o;
}

// ptrans: per-z src [R][C] f32 -> dst [C][R] bf16 (32x32 LDS tiles)
__global__ __launch_bounds__(256)
void ptrans(const float* __restrict__ src, unsigned short* __restrict__ dst,
            int R, int C) {
  __shared__ float ts[32][33];
  const size_t zoff = (size_t)blockIdx.z * R * C;
  src += zoff; dst += zoff;
  const int c0 = blockIdx.x * 32, r0 = blockIdx.y * 32;
  const int x = threadIdx.x & 31, y = threadIdx.x >> 5;   // y in [0,8)
#pragma unroll
  for (int i = 0; i < 4; i++)
    ts[y + 8 * i][x] = src[(size_t)(r0 + y + 8 * i) * C + c0 + x];
  __syncthreads();
#pragma unroll
  for (int i = 0; i < 4; i++)
    dst[(size_t)(c0 + y + 8 * i) * R + r0 + x] = f2bf(ts[x][y + 8 * i]);
}

// ---- unified bf16 tile stage: src row-major [rows][ld], 128x32 tile ----
template <int DS>
__device__ __forceinline__ void stage_bf16(const unsigned short* __restrict__ S, int ld,
                                           int row0, int k0, int tid,
                                           unsigned short* D) {
#pragma unroll
  for (int i = 0; i < 2; i++) {
    const int idx = tid + i * 256;          // 0..511 : 128 rows x 4 chunks of 8
    const int r = idx >> 2, g = idx & 3;
    const uint4 v = *(const uint4*)&S[(size_t)(row0 + r) * ld + k0 + g * 8];
    *(uint4*)&D[r * DS + g * 8] = v;
  }
}

__device__ __forceinline__ void mfma_step(const unsigned short* As, const unsigned short* Bs,
                                          int wy, int wx, int l16, int quad,
                                          floatx4 acc[4][4]) {
  short8 af[4], bfr[4];
#pragma unroll
  for (int i = 0; i < 4; i++) {
    U4 t; t.u = *(const uint4*)&As[(wy * 64 + i * 16 + l16) * LDA_S + quad * 8];
    af[i] = t.s;
  }
#pragma unroll
  for (int j = 0; j < 4; j++) {
    const unsigned short* bp = &Bs[(wx * 64 + j * 16 + l16) * LDB_S + quad * 8];
    uint2 lo = *(const uint2*)bp;
    uint2 hi = *(const uint2*)(bp + 4);
    U4 t; t.u = make_uint4(lo.x, lo.y, hi.x, hi.y);
    bfr[j] = t.s;
  }
#pragma unroll
  for (int i = 0; i < 4; i++)
#pragma unroll
    for (int j = 0; j < 4; j++)
      acc[i][j] = __builtin_amdgcn_mfma_f32_16x16x32_bf16(af[i], bfr[j], acc[i][j], 0, 0, 0);
}

// ===== K1: qk = Htb @ WqkT^T + b_qk -> Q,K (bf16), pure-bf16 staging =====
__global__ __launch_bounds__(256, 2)
void k1_qk(const unsigned short* __restrict__ Htb, const unsigned short* __restrict__ WqkT,
           const float* __restrict__ bias, unsigned short* __restrict__ Q,
           unsigned short* __restrict__ Ko) {
  __shared__ unsigned short As[128 * LDA_S];
  __shared__ unsigned short Bs[128 * LDB_S];
  const int tid = threadIdx.x;
  const int row0 = blockIdx.y * 128, col0 = blockIdx.x * 128;
  const int w = tid >> 6, lane = tid & 63;
  const int wy = w >> 1, wx = w & 1, l16 = lane & 15, quad = lane >> 4;
  floatx4 acc[4][4];
#pragma unroll
  for (int i = 0; i < 4; i++)
#pragma unroll
    for (int j = 0; j < 4; j++)
#pragma unroll
      for (int r = 0; r < 4; r++) acc[i][j][r] = 0.f;

  for (int k0 = 0; k0 < TD; k0 += 32) {
    stage_bf16<LDA_S>(Htb, TD, row0, k0, tid, As);
    stage_bf16<LDB_S>(WqkT, TD, col0, k0, tid, Bs);
    __syncthreads();
    mfma_step(As, Bs, wy, wx, l16, quad, acc);
    __syncthreads();
  }
#pragma unroll
  for (int i = 0; i < 4; i++)
#pragma unroll
    for (int j = 0; j < 4; j++) {
      const int col = col0 + wx * 64 + j * 16 + l16;
      const float bs = bias[col];
#pragma unroll
      for (int r = 0; r < 4; r++) {
        const int row = row0 + wy * 64 + i * 16 + quad * 4 + r;
        const float v = acc[i][j][r] + bs;
        if (col < TD) Q[(size_t)row * TD + col] = f2bf(v);
        else          Ko[(size_t)row * TD + (col - TD)] = f2bf(v);
      }
    }
}

// ==== K2: MFMA scores from global bf16 frags; softmax + channel weights ====
// (R5-validated, unchanged)
#define OB_S 520
__global__ __launch_bounds__(256, 2)
void k2_attn(const unsigned short* __restrict__ Q, const unsigned short* __restrict__ Kb,
             const float* __restrict__ Ml, const float* __restrict__ am,
             unsigned short* __restrict__ Am) {
  __shared__ float smx[16][4];
  __shared__ float4 szd[16][4];
  __shared__ unsigned short obuf[16 * OB_S];
  const int i0 = blockIdx.x;
  const int xcd = i0 & 7, jj = i0 >> 3;
  const int b = xcd + 8 * (jj & 1);
  const int q0 = (jj >> 1) * 16;
  const int tid = threadIdx.x;
  const int w = tid >> 6, lane = tid & 63;
  const int l16 = lane & 15, quad = lane >> 4;
  const int kbase = w * 128;

  const float* amb = am + b * TS;
  float amq[4], amk[8], maskv[8];
#pragma unroll
  for (int r = 0; r < 4; r++) amq[r] = amb[q0 + quad * 4 + r];
#pragma unroll
  for (int kt = 0; kt < 8; kt++) {
    amk[kt] = amb[kbase + kt * 16 + l16];
    maskv[kt] = (1.f - amk[kt]) * (-1e9f);
  }

  unsigned Mpk[TNCH][4][4];
#pragma unroll
  for (int i = 0; i < TNCH; i++)
#pragma unroll
    for (int r = 0; r < 4; r++) {
      const float* Mrow = Ml + ((size_t)((b * TNCH + i) * TS + q0 + quad * 4 + r)) * TS;
#pragma unroll
      for (int kt2 = 0; kt2 < 4; kt2++) {
        const int ke = kbase + kt2 * 32 + l16;
        const float me = Mrow[ke] * amk[kt2 * 2] * amq[r];
        const float mo = Mrow[ke + 16] * amk[kt2 * 2 + 1] * amq[r];
        Mpk[i][r][kt2] = f2bf2(me, mo);
      }
    }

  float acc[TNCH][8][4];
#pragma unroll
  for (int i = 0; i < TNCH; i++)
#pragma unroll
    for (int kt = 0; kt < 8; kt++)
#pragma unroll
      for (int r = 0; r < 4; r++) acc[i][kt][r] = 0.f;

  const unsigned short* qbase = Q + ((size_t)(b * TS + q0 + l16)) * TD + quad * 8;
  const unsigned short* kb0   = Kb + ((size_t)(b * TS + kbase + l16)) * TD + quad * 8;

  for (int h = 0; h < TH; h++) {
    floatx4 sacc[8];
#pragma unroll
    for (int kt = 0; kt < 8; kt++)
#pragma unroll
      for (int r = 0; r < 4; r++) sacc[kt][r] = 0.f;
#pragma unroll
    for (int dk = 0; dk < 2; dk++) {
      U4 a; a.u = *(const uint4*)(qbase + h * TDH + dk * 32);
#pragma unroll
      for (int kt = 0; kt < 8; kt++) {
        U4 bb; bb.u = *(const uint4*)(kb0 + (size_t)kt * 16 * TD + h * TDH + dk * 32);
        sacc[kt] = __builtin_amdgcn_mfma_f32_16x16x32_bf16(a.s, bb.s, sacc[kt], 0, 0, 0);
      }
    }
    float s[8][4];
#pragma unroll
    for (int kt = 0; kt < 8; kt++)
#pragma unroll
      for (int r = 0; r < 4; r++) s[kt][r] = sacc[kt][r] * SCALE + maskv[kt];

    float mxp[4];
#pragma unroll
    for (int r = 0; r < 4; r++) {
      float m = s[0][r];
#pragma unroll
      for (int kt = 1; kt < 8; kt++) m = fmaxf(m, s[kt][r]);
#pragma unroll
      for (int off = 1; off < 16; off <<= 1) m = fmaxf(m, __shfl_xor(m, off));
      mxp[r] = m;
    }
    if (l16 == 0) {
#pragma unroll
      for (int r = 0; r < 4; r++) smx[quad * 4 + r][w] = mxp[r];
    }
    __syncthreads();
    float mxg[4];
#pragma unroll
    for (int r = 0; r < 4; r++) {
      float4 t = *(const float4*)smx[quad * 4 + r];
      mxg[r] = fmaxf(fmaxf(t.x, t.y), fmaxf(t.z, t.w));
    }

    float Zp[4] = {0.f, 0.f, 0.f, 0.f};
#pragma unroll
    for (int kt = 0; kt < 8; kt++)
#pragma unroll
      for (int r = 0; r < 4; r++) {
        float e = __expf(s[kt][r] - mxg[r]);
        s[kt][r] = e;
        Zp[r] += e;
      }
    float dmp[TNCH][4];
#pragma unroll
    for (int i = 0; i < TNCH; i++)
#pragma unroll
      for (int r = 0; r < 4; r++) {
        float d = 0.f;
#pragma unroll
        for (int kt2 = 0; kt2 < 4; kt2++) {
          unsigned u = Mpk[i][r][kt2];
          d += __uint_as_float(u << 16) * s[kt2 * 2][r];
          d += __uint_as_float(u & 0xffff0000u) * s[kt2 * 2 + 1][r];
        }
        dmp[i][r] = d;
      }
#pragma unroll
    for (int r = 0; r < 4; r++) {
#pragma unroll
      for (int off = 1; off < 16; off <<= 1) {
        Zp[r] += __shfl_xor(Zp[r], off);
        dmp[0][r] += __shfl_xor(dmp[0][r], off);
        dmp[1][r] += __shfl_xor(dmp[1][r], off);
        dmp[2][r] += __shfl_xor(dmp[2][r], off);
      }
    }
    if (l16 == 0) {
#pragma unroll
      for (int r = 0; r < 4; r++)
        szd[quad * 4 + r][w] = make_float4(Zp[r], dmp[0][r], dmp[1][r], dmp[2][r]);
    }
    __syncthreads();
#pragma unroll
    for (int r = 0; r < 4; r++) {
      float4 t0 = szd[quad * 4 + r][0];
      float4 t1 = szd[quad * 4 + r][1];
      float4 t2 = szd[quad * 4 + r][2];
      float4 t3 = szd[quad * 4 + r][3];
      const float Z  = t0.x + t1.x + t2.x + t3.x;
      const float w0 = 1.f / (t0.y + t1.y + t2.y + t3.y + 1e-10f * Z);
      const float w1 = 1.f / (t0.z + t1.z + t2.z + t3.z + 1e-10f * Z);
      const float w2 = 1.f / (t0.w + t1.w + t2.w + t3.w + 1e-10f * Z);
#pragma unroll
      for (int kt = 0; kt < 8; kt++) {
        acc[0][kt][r] += s[kt][r] * w0;
        acc[1][kt][r] += s[kt][r] * w1;
        acc[2][kt][r] += s[kt][r] * w2;
      }
    }
  }

  const float inv_h = 1.f / (float)TH;
  for (int i = 0; i < TNCH; i++) {
#pragma unroll
    for (int r = 0; r < 4; r++) {
      const int q = q0 + quad * 4 + r;
      const float* Mrow = Ml + ((size_t)((b * TNCH + i) * TS + q)) * TS;
#pragma unroll
      for (int kt = 0; kt < 8; kt++) {
        const int k = kbase + kt * 16 + l16;
        const float mv = Mrow[k] * amk[kt] * amq[r];
        obuf[(quad * 4 + r) * OB_S + k] = f2bf(mv * acc[i][kt][r] * inv_h);
      }
    }
    __syncthreads();
#pragma unroll
    for (int it = 0; it < 4; it++) {
      const int idx = tid + it * 256;
      const int row = idx >> 6, c16 = idx & 63;
      const uint4 v = *(const uint4*)&obuf[row * OB_S + c16 * 8];
      *(uint4*)&Am[((size_t)((i * TB + b) * TS + q0 + row)) * TS + c16 * 8] = v;
    }
    __syncthreads();
  }
}

// ===== K3: G[z] = Am[z] @ HtbT[b]^T -> bf16, pure-bf16 staging =====
__global__ __launch_bounds__(256, 2)
void k3_feat(const unsigned short* __restrict__ Am, const unsigned short* __restrict__ HtbT,
             unsigned short* __restrict__ G) {
  __shared__ unsigned short As[128 * LDA_S];
  __shared__ unsigned short Bs[128 * LDB_S];
  const int z = blockIdx.z;
  const int b = z & 15;
  const unsigned short* A  = Am + (size_t)z * TS * TS;
  const unsigned short* Bt = HtbT + (size_t)b * TD * TS;
  unsigned short* C = G + (size_t)z * TS * TD;
  const int tid = threadIdx.x;
  const int row0 = blockIdx.y * 128, col0 = blockIdx.x * 128;
  const int w = tid >> 6, lane = tid & 63;
  const int wy = w >> 1, wx = w & 1, l16 = lane & 15, quad = lane >> 4;
  floatx4 acc[4][4];
#pragma unroll
  for (int i = 0; i < 4; i++)
#pragma unroll
    for (int j = 0; j < 4; j++)
#pragma unroll
      for (int r = 0; r < 4; r++) acc[i][j][r] = 0.f;

  for (int k0 = 0; k0 < TS; k0 += 32) {
    stage_bf16<LDA_S>(A, TS, row0, k0, tid, As);
    stage_bf16<LDB_S>(Bt, TS, col0, k0, tid, Bs);
    __syncthreads();
    mfma_step(As, Bs, wy, wx, l16, quad, acc);
    __syncthreads();
  }
#pragma unroll
  for (int i = 0; i < 4; i++)
#pragma unroll
    for (int j = 0; j < 4; j++) {
      const int col = col0 + wx * 64 + j * 16 + l16;
#pragma unroll
      for (int r = 0; r < 4; r++) {
        const int row = row0 + wy * 64 + i * 16 + quad * 4 + r;
        C[(size_t)row * TD + col] = f2bf(acc[i][j][r]);
      }
    }
}

// == K4: out = mean_ch relu(G_ch @ WgT_ch^T + bg_ch) * am, pure-bf16 staging ==
__global__ __launch_bounds__(256, 2)
void k4_out(const unsigned short* __restrict__ G, const unsigned short* __restrict__ WgT,
            const float* __restrict__ bg, const float* __restrict__ am,
            float* __restrict__ out) {
  __shared__ unsigned short As[128 * LDA_S];
  __shared__ unsigned short Bs[128 * LDB_S];
  const int tid = threadIdx.x;
  const int row0 = blockIdx.y * 128, col0 = blockIdx.x * 128;
  const int w = tid >> 6, lane = tid & 63;
  const int wy = w >> 1, wx = w & 1, l16 = lane & 15, quad = lane >> 4;
  float osum[4][4][4];
#pragma unroll
  for (int i = 0; i < 4; i++)
#pragma unroll
    for (int j = 0; j < 4; j++)
#pragma unroll
      for (int r = 0; r < 4; r++) osum[i][j][r] = 0.f;

  for (int ch = 0; ch < TNCH; ch++) {
    const unsigned short* A  = G + (size_t)ch * (TB * TS) * TD;
    const unsigned short* Bt = WgT + (size_t)ch * TD * TD;
    floatx4 acc[4][4];
#pragma unroll
    for (int i = 0; i < 4; i++)
#pragma unroll
      for (int j = 0; j < 4; j++)
#pragma unroll
        for (int r = 0; r < 4; r++) acc[i][j][r] = 0.f;

    for (int k0 = 0; k0 < TD; k0 += 32) {
      stage_bf16<LDA_S>(A, TD, row0, k0, tid, As);
      stage_bf16<LDB_S>(Bt, TD, col0, k0, tid, Bs);
      __syncthreads();
      mfma_step(As, Bs, wy, wx, l16, quad, acc);
      __syncthreads();
    }
#pragma unroll
    for (int i = 0; i < 4; i++)
#pragma unroll
      for (int j = 0; j < 4; j++) {
        const int col = col0 + wx * 64 + j * 16 + l16;
        const float bs = bg[ch * TD + col];
#pragma unroll
        for (int r = 0; r < 4; r++)
          osum[i][j][r] += fmaxf(acc[i][j][r] + bs, 0.f);
      }
  }
#pragma unroll
  for (int i = 0; i < 4; i++)
#pragma unroll
    for (int r = 0; r < 4; r++) {
      const int row = row0 + wy * 64 + i * 16 + quad * 4 + r;
      const float amr = am[row] * (1.f / 3.f);
#pragma unroll
      for (int j = 0; j < 4; j++) {
        const int col = col0 + wx * 64 + j * 16 + l16;
        out[(size_t)row * TD + col] = osum[i][j][r] * amr;
      }
    }
}

extern "C" void kernel_launch(void* const* d_in, const int* in_sizes, int n_in,
                              void* d_out, int out_size, void* d_ws, size_t ws_size,
                              hipStream_t stream) {
  const float* Ht    = (const float*)d_in[0];
  const float* Ml    = (const float*)d_in[1];
  const float* am    = (const float*)d_in[2];
  const float* W_qk  = (const float*)d_in[3];
  const float* b_qk  = (const float*)d_in[4];
  const float* W_gat = (const float*)d_in[5];
  const float* b_gat = (const float*)d_in[6];
  float* out = (float*)d_out;

  // ws layout (ushorts):
  //   Q     [0,          6291456)
  //   K     [6291456,   12582912)
  //   Htb   [12582912,  18874368)   bf16(Ht), A-operand for k1
  //   HtbT  [18874368,  25165824)   per-b [768][512], B-operand for k3
  //   WqkT  [25165824,  26345472)   [1536][768]
  //   WgT   [26345472,  28114944)   [3][768][768]
  //   Am    [28114944,  40697856)
  //   G     [0,         18874368)   overlays Q/K/Htb (dead after k2/k1)
  unsigned short* base = (unsigned short*)d_ws;
  const size_t SEG = (size_t)TB * TS * TD;            // 6291456
  unsigned short* Q    = base;
  unsigned short* Kw   = base + SEG;
  unsigned short* Htb  = base + 2 * SEG;
  unsigned short* HtbT = base + 3 * SEG;
  unsigned short* WqkT = base + 4 * SEG;
  unsigned short* WgT  = WqkT + (size_t)TD * 2 * TD;
  unsigned short* Am   = WgT + (size_t)TNCH * TD * TD;
  unsigned short* G    = base;

  // prep: bf16 conversions + transposes (one-shot, ~100 MB traffic)
  pconv <<<dim3(3072), 256, 0, stream>>>(Ht, Htb);
  ptrans<<<dim3(24, 16, 16), 256, 0, stream>>>(Ht, HtbT, TS, TD);
  ptrans<<<dim3(48, 24, 1),  256, 0, stream>>>(W_qk, WqkT, TD, 2 * TD);
  ptrans<<<dim3(24, 24, 3),  256, 0, stream>>>(W_gat, WgT, TD, TD);

  k1_qk  <<<dim3(12, 64), 256, 0, stream>>>(Htb, WqkT, b_qk, Q, Kw);
  k2_attn<<<dim3(512), 256, 0, stream>>>(Q, Kw, Ml, am, Am);
  k3_feat<<<dim3(6, 4, 48), 256, 0, stream>>>(Am, HtbT, G);
  k4_out <<<dim3(6, 64), 256, 0, stream>>>(G, WgT, b_gat, am, out);
}